// Round 17
// baseline (265.263 us; speedup 1.0000x reference)
//
#include <hip/hip_runtime.h>
#include <hip/hip_bf16.h>
#include <cstdint>
#include <cstddef>

#define DEVINL __device__ __forceinline__

typedef float f32x2 __attribute__((ext_vector_type(2)));
typedef float f32x4 __attribute__((ext_vector_type(4)));
typedef float f32x16 __attribute__((ext_vector_type(16)));
typedef short s16x8 __attribute__((ext_vector_type(8)));
typedef short s16x4 __attribute__((ext_vector_type(4)));

static constexpr int Sd = 2048;   // sequence
static constexpr int Hd = 1024;   // hidden
static constexpr int NHd = 16;    // heads
static constexpr int Dd = 64;     // head dim
static constexpr int N3 = 3072;   // 3*H

DEVINL float bf2f(short u){
  unsigned int t = ((unsigned int)(unsigned short)u) << 16;
  float f; __builtin_memcpy(&f, &t, 4); return f;
}
DEVINL short f2bf(float f){
  unsigned int t; __builtin_memcpy(&t, &f, 4);
  unsigned int r = t + 0x7FFFu + ((t >> 16) & 1u);   // RNE
  return (short)(r >> 16);
}

DEVINL void gld16(const short* g, short* l){
  __builtin_amdgcn_global_load_lds((const __attribute__((address_space(1))) unsigned int*)g,
                                   (__attribute__((address_space(3))) unsigned int*)l, 16, 0, 0);
}

DEVINL int cvtpk(float lo, float hi){
  int r; asm("v_cvt_pk_bf16_f32 %0, %1, %2" : "=v"(r) : "v"(lo), "v"(hi)); return r;
}

DEVINL float fexp2(float x){
#if __has_builtin(__builtin_amdgcn_exp2f)
  return __builtin_amdgcn_exp2f(x);
#else
  return exp2f(x);
#endif
}

DEVINL f32x16 z16(){
  f32x16 v;
  #pragma unroll
  for (int i=0;i<16;i++) v[i]=0.f;
  return v;
}

// ---------------- prep: LayerNorm (blocks 0..8191) | W cast+transpose (blocks 8192..11263) ----
__global__ __launch_bounds__(256) void prep_kernel(const float* __restrict__ x,
                                                   const float* __restrict__ lw,
                                                   const float* __restrict__ lb,
                                                   short* __restrict__ h,
                                                   const float* __restrict__ w,
                                                   short* __restrict__ wT){
  int bid = blockIdx.x, tid = threadIdx.x;
  if (bid < 8192){
    const float* xr = x + (size_t)bid * Hd;
    f32x4 v = *(const f32x4*)(xr + tid*4);
    float s1 = v[0]+v[1]+v[2]+v[3];
    float s2 = v[0]*v[0]+v[1]*v[1]+v[2]*v[2]+v[3]*v[3];
    #pragma unroll
    for (int off = 1; off < 64; off <<= 1){ s1 += __shfl_xor(s1, off); s2 += __shfl_xor(s2, off); }
    __shared__ float red[8];
    if ((tid & 63) == 0){ red[(tid>>6)*2] = s1; red[(tid>>6)*2+1] = s2; }
    __syncthreads();
    s1 = red[0]+red[2]+red[4]+red[6];
    s2 = red[1]+red[3]+red[5]+red[7];
    float mu = s1 * (1.0f/Hd);
    float rstd = rsqrtf(s2*(1.0f/Hd) - mu*mu + 1e-12f);
    f32x4 wv = *(const f32x4*)(lw + tid*4);
    f32x4 bv = *(const f32x4*)(lb + tid*4);
    s16x4 o;
    #pragma unroll
    for (int i=0;i<4;i++) o[i] = f2bf((v[i]-mu)*rstd*wv[i] + bv[i]);
    *(s16x4*)(h + (size_t)bid*Hd + tid*4) = o;
  } else {
    __shared__ float t[32][33];
    int cid = bid - 8192;                            // 0..3071
    int n0 = (cid % 96)*32, k0 = (cid / 96)*32;
    int tx = tid & 31, ty = tid >> 5;                // (32,8)
    #pragma unroll
    for (int i=0;i<4;i++) t[ty + i*8][tx] = w[(size_t)(k0 + ty + i*8)*N3 + n0 + tx];
    __syncthreads();
    #pragma unroll
    for (int i=0;i<4;i++) wT[(size_t)(n0 + ty + i*8)*Hd + k0 + tx] = f2bf(t[tx][ty + i*8]);
  }
}

// ---------------- QKV GEMM: BM=256 x BN=128 x BK=64, 3-buffer ring, counted vmcnt ------
// R16 (kept): R12's ring schedule at 256x128x64. 768 blocks (3 exact CU rounds),
// 512 thr / 8 waves (4m x 2n), acc[4][4]. 3-bit chunk-XOR swizzle. vmcnt(6) counted
// waits; one raw s_barrier per K-tile. Epilogue: fused RoPE (shfl_xor(1) + LDS
// (sin,cos) pair table [256][66]); V written transposed. Part-pure: part = nt>>3.
__global__ __launch_bounds__(512, 2) void gemm_kernel(const short* __restrict__ A,
                                                      const short* __restrict__ Bt,
                                                      const float* __restrict__ bias,
                                                      const float* __restrict__ sp,
                                                      short* __restrict__ qo,
                                                      short* __restrict__ ko,
                                                      short* __restrict__ vo){
  __shared__ alignas(16) char smem[147456];          // 3 x (A 32KB + B 16KB); epilogue: sps2
  float* sps2 = (float*)smem;                        // [256][66] f32 interleaved pairs (67.6KB)
  int bid = blockIdx.x;
  int xcd = bid & 7, idx = bid >> 3;                 // idx 0..95
  int mt = xcd*4 + (idx & 3), nt = idx >> 2;         // mt 0..31, nt 0..23
  int m0 = mt*256, n0 = nt*128;
  int tid = threadIdx.x, lane = tid & 63, wv = tid >> 6;
  int l15 = lane & 15, lq = lane >> 4;
  int wr = wv >> 1, wc = wv & 1;                     // wr 0..3 (64-row slabs), wc 0..1 (64-col)
  f32x4 zero = {0.f,0.f,0.f,0.f};
  f32x4 acc[4][4];
  #pragma unroll
  for (int m=0;m<4;m++)
    #pragma unroll
    for (int n=0;n<4;n++) acc[m][n] = zero;
  const short* srcA[4]; const short* srcB[2];
  #pragma unroll
  for (int i=0;i<4;i++){
    int c = tid + i*512, r = c >> 3, g = (c & 7) ^ (r & 7);
    srcA[i] = A + (size_t)(m0 + r)*Hd + g*8;
  }
  #pragma unroll
  for (int i=0;i<2;i++){
    int c = tid + i*512, r = c >> 3, g = (c & 7) ^ (r & 7);
    srcB[i] = Bt + (size_t)(n0 + r)*Hd + g*8;
  }
  int rsw = l15 & 7;                                 // read-side chunk XOR (row&7 = l15&7)

#define GSTAGE(q_, t_) do { \
    short* bA = (short*)(smem + (q_)*49152); \
    short* bB = bA + 16384; \
    _Pragma("unroll") \
    for (int i=0;i<4;i++) gld16(srcA[i] + (t_)*64, bA + wv*512 + i*4096); \
    _Pragma("unroll") \
    for (int i=0;i<2;i++) gld16(srcB[i] + (t_)*64, bB + wv*512 + i*4096); \
  } while(0)

#define KBODY(q_) do { \
    const short* bA = (const short*)(smem + (q_)*49152); \
    const short* bB = bA + 16384; \
    _Pragma("unroll") \
    for (int kh=0;kh<2;kh++){ \
      s16x8 bf[4]; \
      _Pragma("unroll") \
      for (int n=0;n<4;n++) \
        bf[n] = *(const s16x8*)(bB + (wc*64 + n*16 + l15)*64 + (((kh*4+lq)^rsw)*8)); \
      __builtin_amdgcn_s_setprio(1); \
      _Pragma("unroll") \
      for (int m=0;m<4;m++){ \
        s16x8 af = *(const s16x8*)(bA + (wr*64 + m*16 + l15)*64 + (((kh*4+lq)^rsw)*8)); \
        _Pragma("unroll") \
        for (int n=0;n<4;n++) \
          acc[m][n] = __builtin_amdgcn_mfma_f32_16x16x32_bf16(af, bf[n], acc[m][n], 0, 0, 0); \
      } \
      __builtin_amdgcn_s_setprio(0); \
    } \
  } while(0)

  GSTAGE(0, 0);
  GSTAGE(1, 1);
  int bq = 0;
  for (int t = 0; t < 15; ++t){
    asm volatile("s_waitcnt vmcnt(6)" ::: "memory"); // tile t landed; t+1's 6 stay in flight
    __builtin_amdgcn_s_barrier();                    // cross-wave visibility + buf-reuse safety
    __builtin_amdgcn_sched_barrier(0);
    if (t < 14){
      int bn = bq + 2; if (bn >= 3) bn -= 3;
      GSTAGE(bn, t+2);                               // into buffer consumed at t-1
    }
    KBODY(bq);
    ++bq; if (bq >= 3) bq = 0;
  }
  asm volatile("s_waitcnt vmcnt(0)" ::: "memory");   // peel t=15: full drain
  __builtin_amdgcn_s_barrier();
  __builtin_amdgcn_sched_barrier(0);
  KBODY(bq);
#undef GSTAGE
#undef KBODY
  // ---- epilogue (block-uniform part) ----
  int part = nt >> 3;                                // 0:q 1:k 2:v
  if (part == 2){
    #pragma unroll
    for (int n=0;n<4;n++){
      int c = n0 + wc*64 + n*16 + l15;
      float bv = bias[c];
      int hh = (c >> 6) & 15, d = c & 63;
      #pragma unroll
      for (int m=0;m<4;m++){
        int r0 = m0 + wr*64 + m*16 + lq*4;           // 4 consecutive rows, same b
        int b = r0 >> 11, s0r = r0 & 2047;
        s16x4 o;
        #pragma unroll
        for (int j=0;j<4;j++) o[j] = f2bf(acc[m][n][j] + bv);
        *(s16x4*)(vo + (((size_t)((b*NHd + hh)*Dd + d)) << 11) + s0r) = o;
      }
    }
  } else {
    __syncthreads();                                 // all waves done with ring buffers
    const float* gsp = sp + (size_t)(m0 & 2047)*64;  // block's 256 rows of sin/cos
    #pragma unroll
    for (int u4=0; u4<4; ++u4){
      int u = tid + u4*512;                          // 0..2047
      int sl = u >> 3, dh4 = u & 7;
      f32x4 s4v = *(const f32x4*)(gsp + sl*64 + dh4*4);
      f32x4 c4v = *(const f32x4*)(gsp + sl*64 + 32 + dh4*4);
      float* w8 = sps2 + sl*66 + dh4*8;
      f32x2 p0 = {s4v[0], c4v[0]}, p1 = {s4v[1], c4v[1]};
      f32x2 p2 = {s4v[2], c4v[2]}, p3 = {s4v[3], c4v[3]};
      *(f32x2*)(w8)     = p0; *(f32x2*)(w8 + 2) = p1;
      *(f32x2*)(w8 + 4) = p2; *(f32x2*)(w8 + 6) = p3;
    }
    __syncthreads();
    short* dst = part == 0 ? qo : ko;
    float postscale = part == 0 ? 0.18033688011112042f : 1.0f;  // q: 1/sqrt(64)*log2(e)
    float sgnmul = (l15 & 1) ? 1.0f : -1.0f;         // d parity == l15 parity
    float bvv[4]; int hhv[4], dv[4];
    #pragma unroll
    for (int n=0;n<4;n++){
      int c = n0 + wc*64 + n*16 + l15;
      bvv[n] = bias[c]; hhv[n] = (c >> 6) & 15; dv[n] = c & 63;
    }
    int dh0 = l15 >> 1;                              // d>>1 = n*8 + (l15>>1)
    #pragma unroll
    for (int m=0;m<4;m++){
      #pragma unroll
      for (int j=0;j<4;j++){
        int sl = wr*64 + m*16 + lq*4 + j;            // local row 0..255
        const float* sb = sps2 + sl*66 + dh0*2;
        int r = m0 + sl;
        int b = r >> 11, s = r & 2047;
        #pragma unroll
        for (int n=0;n<4;n++){
          f32x2 sc = *(const f32x2*)(sb + n*16);     // (sin, cos) for d = n*16+l15
          float x = acc[m][n][j] + bvv[n];
          float xp = __shfl_xor(x, 1);               // partner column d^1 (post-bias)
          float y = (x*sc[1] + sgnmul*xp*sc[0]) * postscale;
          dst[(((size_t)((b*NHd + hhv[n])*Sd + s)) << 6) + dv[n]] = f2bf(y);
        }
      }
    }
  }
}

// ---------------- Flash attention: 8 waves x 32 q-rows, K staged / V DIRECT ----------
// R17: V read directly from global/L2 (guide m169: staging L2-resident V is pure
// overhead). K/V per XCD = 4MB = L2 (8 bh pinned by block swizzle). V addresses
// depend only on loop indices -> loads hoist above softmax, L2 latency hides under
// QK+softmax; no swizzle (L2 has no banks). Removes: vbuf (32KB LDS), V staging,
// half the ds_read traffic and ~half the bank conflicts. Zero new loop state.
__global__ __launch_bounds__(512, 4) void attn_kernel(const short* __restrict__ q,
                                                      const short* __restrict__ k,
                                                      const short* __restrict__ vT,
                                                      float* __restrict__ out){
  __shared__ alignas(16) short kbuf[2][8192];        // [128 kv][64 d], swizzled (32 KB)
  int bid = blockIdx.x;
  int xcd = bid & 7, w = bid >> 3;                   // same-bh blocks share an XCD's L2
  int bh = xcd*8 + (w >> 3), qb = w & 7;
  int tid = threadIdx.x, lane = tid & 63, wv = tid >> 6;
  int l31 = lane & 31, hi = lane >> 5;
  const short* kp = k  + ((size_t)bh << 17);
  const short* vp = vT + ((size_t)bh << 17);
  int qrow = qb*256 + wv*32 + l31;
  const short* qp = q + ((size_t)bh << 17) + (size_t)qrow*64;
  s16x8 qf[4];                                       // B-frag: col=q(lane&31), k = d = 16*kk+8*hi+i
  #pragma unroll
  for (int kk=0;kk<4;kk++) qf[kk] = *(const s16x8*)(qp + kk*16 + hi*8);
  int kc0 = tid,      kr0 = kc0 >> 3;
  int kc1 = tid+512,  kr1 = kc1 >> 3;
  int koff0 = kr0*64 + ((kc0 ^ kr0) & 7)*8;
  int koff1 = kr1*64 + ((kc1 ^ kr1) & 7)*8;
  // V^T direct-read bases: rows d = l31 (ot0) and 32+l31 (ot1); kv column walks t*128+h*64+slot*8
  const short* vrow0 = vp + (size_t)l31*2048;
  const short* vrow1 = vp + (size_t)(32 + l31)*2048;

  f32x16 ot0 = z16(), ot1 = z16();                   // O^T: col=q, row = d
  float m = -1e30f, lr = 0.f;                        // lr = own-half partial sum
  int rsw = (l31 & 7);                               // read-side chunk XOR (K only)

#define STAGE(nb, t) do { \
    gld16(kp + (size_t)(t)*8192 + koff0, &kbuf[nb][0]    + wv*512); \
    gld16(kp + (size_t)(t)*8192 + koff1, &kbuf[nb][4096] + wv*512); \
  } while(0)

  STAGE(0, 0);
  __syncthreads();

  for (int t = 0; t < 16; ++t){
    int cur = t & 1;
    if (t < 15) STAGE(cur^1, t+1);                   // drained by barrier at end of t
    #pragma unroll
    for (int h = 0; h < 2; ++h){
      const short* kb = &kbuf[cur][h*4096];
      const short* vc0 = vrow0 + t*128 + h*64;       // this half's 64 kv columns
      const short* vc1 = vrow1 + t*128 + h*64;
      // ---- S^T = K . Q^T  (two 32x32 kv tiles, contraction d=64) ----
      f32x16 s0 = z16(), s1 = z16();
      __builtin_amdgcn_s_setprio(1);
      #pragma unroll
      for (int kk=0;kk<4;kk++){
        s16x8 kf0 = *(const s16x8*)(kb + l31*64       + (((kk*2 + hi) ^ rsw)*8));
        s0 = __builtin_amdgcn_mfma_f32_32x32x16_bf16(kf0, qf[kk], s0, 0, 0, 0);
        s16x8 kf1 = *(const s16x8*)(kb + (32+l31)*64  + (((kk*2 + hi) ^ rsw)*8));
        s1 = __builtin_amdgcn_mfma_f32_32x32x16_bf16(kf1, qf[kk], s1, 0, 0, 0);
      }
      __builtin_amdgcn_s_setprio(0);
      // ---- V fragments: direct global loads (independent of softmax -> issue early) ----
      s16x8 vf0[4], vf1[4];
      #pragma unroll
      for (int s4=0;s4<4;s4++){
        vf0[s4] = *(const s16x8*)(vc0 + (s4*2 + hi)*8);
        vf1[s4] = *(const s16x8*)(vc1 + (s4*2 + hi)*8);
      }
      // ---- online softmax, lane-local per q-row (log2 domain) ----
      float tm[16];
      #pragma unroll
      for (int i=0;i<16;i++) tm[i] = fmaxf(s0[i], s1[i]);
      #pragma unroll
      for (int off=8; off>=1; off>>=1)
        #pragma unroll
        for (int i=0;i<off;i++) tm[i] = fmaxf(tm[i], tm[i+off]);
      float pmax = fmaxf(tm[0], __shfl_xor(tm[0], 32));
      if (!__all(pmax - m <= 8.0f)){                 // defer-max (T13)
        float mn = fmaxf(m, pmax);
        float al = fexp2(m - mn);
        m = mn; lr *= al;
        #pragma unroll
        for (int i=0;i<16;i++){ ot0[i] *= al; ot1[i] *= al; }
      }
      #pragma unroll
      for (int i=0;i<16;i++){ s0[i] = fexp2(s0[i]-m); s1[i] = fexp2(s1[i]-m); }
      float ra[16];
      #pragma unroll
      for (int i=0;i<16;i++) ra[i] = s0[i] + s1[i];
      #pragma unroll
      for (int off=8; off>=1; off>>=1)
        #pragma unroll
        for (int i=0;i<off;i++) ra[i] += ra[i+off];
      lr += ra[0];                                   // own-half partial; combined in epilogue
      // ---- P^T -> bf16 B-frags, O^T += V^T . P^T ----
      #pragma unroll
      for (int s4=0;s4<4;s4++){
        int base = (s4 & 1) * 8;
        int pkA0, pkA1, pkB0, pkB1;
        if (s4 < 2){
          pkA0 = cvtpk(s0[base],   s0[base+1]); pkA1 = cvtpk(s0[base+2], s0[base+3]);
          pkB0 = cvtpk(s0[base+4], s0[base+5]); pkB1 = cvtpk(s0[base+6], s0[base+7]);
        } else {
          pkA0 = cvtpk(s1[base],   s1[base+1]); pkA1 = cvtpk(s1[base+2], s1[base+3]);
          pkB0 = cvtpk(s1[base+4], s1[base+5]); pkB1 = cvtpk(s1[base+6], s1[base+7]);
        }
        int r0 = __shfl_xor(hi ? pkA0 : pkB0, 32);
        int r1 = __shfl_xor(hi ? pkA1 : pkB1, 32);
        union { int wq[4]; s16x8 v8; } u;
        u.wq[0] = hi ? r0   : pkA0;
        u.wq[1] = hi ? r1   : pkA1;
        u.wq[2] = hi ? pkB0 : r0;
        u.wq[3] = hi ? pkB1 : r1;
        __builtin_amdgcn_s_setprio(1);
        ot0 = __builtin_amdgcn_mfma_f32_32x32x16_bf16(vf0[s4], u.v8, ot0, 0, 0, 0);
        ot1 = __builtin_amdgcn_mfma_f32_32x32x16_bf16(vf1[s4], u.v8, ot1, 0, 0, 0);
        __builtin_amdgcn_s_setprio(0);
      }
    }
    __syncthreads();                                 // drains vmcnt (K stage) + all waves done with cur
  }
#undef STAGE
  // ---- epilogue: combine halves' lr once; out[b][s=q][h*64 + d] ----
  float lrt = lr + __shfl_xor(lr, 32);
  float inv = 1.0f / lrt;
  int b = bh >> 4, hh = bh & 15;
  float* orow = out + ((size_t)(b*Sd + qrow) << 10) + hh*64;
  #pragma unroll
  for (int g=0; g<4; ++g){
    f32x4 w0, w1;
    #pragma unroll
    for (int j=0;j<4;j++){ w0[j] = ot0[4*g+j]*inv; w1[j] = ot1[4*g+j]*inv; }
    *(f32x4*)(orow + g*8 + 4*hi)      = w0;
    *(f32x4*)(orow + 32 + g*8 + 4*hi) = w1;
  }
}

extern "C" void kernel_launch(void* const* d_in, const int* in_sizes, int n_in,
                              void* d_out, int out_size, void* d_ws, size_t ws_size,
                              hipStream_t stream){
  const float* hs = (const float*)d_in[0];
  const float* sp = (const float*)d_in[1];
  const float* lw = (const float*)d_in[2];
  const float* lb = (const float*)d_in[3];
  const float* wq = (const float*)d_in[4];
  const float* bq = (const float*)d_in[5];
  float* out = (float*)d_out;
  char* ws = (char*)d_ws;
  short* h   = (short*)(ws);
  short* wT  = (short*)(ws + 16777216);
  short* qb_ = (short*)(ws + 23068672);
  short* kb_ = (short*)(ws + 23068672 + 16777216);
  short* vTb = (short*)(ws + 23068672 + 33554432);   // [bh][D][S], written by GEMM epilogue

  hipLaunchKernelGGL(prep_kernel,  dim3(11264),   dim3(256),   0, stream, hs, lw, lb, h, wq, wT);
  hipLaunchKernelGGL(gemm_kernel,  dim3(768),     dim3(512),   0, stream, h, wT, bq, sp, qb_, kb_, vTb);
  hipLaunchKernelGGL(attn_kernel,  dim3(512),     dim3(512),   0, stream, qb_, kb_, vTb, out);
}

// Round 18
// 171.960 us; speedup vs baseline: 1.5426x; 1.5426x over previous
//
#include <hip/hip_runtime.h>
#include <hip/hip_bf16.h>
#include <cstdint>
#include <cstddef>

#define DEVINL __device__ __forceinline__

typedef float f32x2 __attribute__((ext_vector_type(2)));
typedef float f32x4 __attribute__((ext_vector_type(4)));
typedef float f32x16 __attribute__((ext_vector_type(16)));
typedef short s16x8 __attribute__((ext_vector_type(8)));
typedef short s16x4 __attribute__((ext_vector_type(4)));

static constexpr int Sd = 2048;   // sequence
static constexpr int Hd = 1024;   // hidden
static constexpr int NHd = 16;    // heads
static constexpr int Dd = 64;     // head dim
static constexpr int N3 = 3072;   // 3*H

DEVINL float bf2f(short u){
  unsigned int t = ((unsigned int)(unsigned short)u) << 16;
  float f; __builtin_memcpy(&f, &t, 4); return f;
}
DEVINL short f2bf(float f){
  unsigned int t; __builtin_memcpy(&t, &f, 4);
  unsigned int r = t + 0x7FFFu + ((t >> 16) & 1u);   // RNE
  return (short)(r >> 16);
}

DEVINL void gld16(const short* g, short* l){
  __builtin_amdgcn_global_load_lds((const __attribute__((address_space(1))) unsigned int*)g,
                                   (__attribute__((address_space(3))) unsigned int*)l, 16, 0, 0);
}

DEVINL int cvtpk(float lo, float hi){
  int r; asm("v_cvt_pk_bf16_f32 %0, %1, %2" : "=v"(r) : "v"(lo), "v"(hi)); return r;
}

DEVINL float fexp2(float x){
#if __has_builtin(__builtin_amdgcn_exp2f)
  return __builtin_amdgcn_exp2f(x);
#else
  return exp2f(x);
#endif
}

DEVINL f32x16 z16(){
  f32x16 v;
  #pragma unroll
  for (int i=0;i<16;i++) v[i]=0.f;
  return v;
}

// ---------------- prep: LayerNorm (blocks 0..8191) | W cast+transpose (blocks 8192..11263) ----
__global__ __launch_bounds__(256) void prep_kernel(const float* __restrict__ x,
                                                   const float* __restrict__ lw,
                                                   const float* __restrict__ lb,
                                                   short* __restrict__ h,
                                                   const float* __restrict__ w,
                                                   short* __restrict__ wT){
  int bid = blockIdx.x, tid = threadIdx.x;
  if (bid < 8192){
    const float* xr = x + (size_t)bid * Hd;
    f32x4 v = *(const f32x4*)(xr + tid*4);
    float s1 = v[0]+v[1]+v[2]+v[3];
    float s2 = v[0]*v[0]+v[1]*v[1]+v[2]*v[2]+v[3]*v[3];
    #pragma unroll
    for (int off = 1; off < 64; off <<= 1){ s1 += __shfl_xor(s1, off); s2 += __shfl_xor(s2, off); }
    __shared__ float red[8];
    if ((tid & 63) == 0){ red[(tid>>6)*2] = s1; red[(tid>>6)*2+1] = s2; }
    __syncthreads();
    s1 = red[0]+red[2]+red[4]+red[6];
    s2 = red[1]+red[3]+red[5]+red[7];
    float mu = s1 * (1.0f/Hd);
    float rstd = rsqrtf(s2*(1.0f/Hd) - mu*mu + 1e-12f);
    f32x4 wv = *(const f32x4*)(lw + tid*4);
    f32x4 bv = *(const f32x4*)(lb + tid*4);
    s16x4 o;
    #pragma unroll
    for (int i=0;i<4;i++) o[i] = f2bf((v[i]-mu)*rstd*wv[i] + bv[i]);
    *(s16x4*)(h + (size_t)bid*Hd + tid*4) = o;
  } else {
    __shared__ float t[32][33];
    int cid = bid - 8192;                            // 0..3071
    int n0 = (cid % 96)*32, k0 = (cid / 96)*32;
    int tx = tid & 31, ty = tid >> 5;                // (32,8)
    #pragma unroll
    for (int i=0;i<4;i++) t[ty + i*8][tx] = w[(size_t)(k0 + ty + i*8)*N3 + n0 + tx];
    __syncthreads();
    #pragma unroll
    for (int i=0;i<4;i++) wT[(size_t)(n0 + ty + i*8)*Hd + k0 + tx] = f2bf(t[tx][ty + i*8]);
  }
}

// ---------------- QKV GEMM: BM=256 x BN=128 x BK=64, 3-buffer ring, counted vmcnt ------
// R16-proven: R12's ring schedule at 256x128x64. 768 blocks (3 exact CU rounds),
// 512 thr / 8 waves (4m x 2n), acc[4][4]. 3-bit chunk-XOR swizzle. vmcnt(6) counted
// waits; one raw s_barrier per K-tile. Epilogue: fused RoPE (shfl_xor(1) + LDS
// (sin,cos) pair table [256][66]); V written transposed. Part-pure: part = nt>>3.
__global__ __launch_bounds__(512, 2) void gemm_kernel(const short* __restrict__ A,
                                                      const short* __restrict__ Bt,
                                                      const float* __restrict__ bias,
                                                      const float* __restrict__ sp,
                                                      short* __restrict__ qo,
                                                      short* __restrict__ ko,
                                                      short* __restrict__ vo){
  __shared__ alignas(16) char smem[147456];          // 3 x (A 32KB + B 16KB); epilogue: sps2
  float* sps2 = (float*)smem;                        // [256][66] f32 interleaved pairs (67.6KB)
  int bid = blockIdx.x;
  int xcd = bid & 7, idx = bid >> 3;                 // idx 0..95
  int mt = xcd*4 + (idx & 3), nt = idx >> 2;         // mt 0..31, nt 0..23
  int m0 = mt*256, n0 = nt*128;
  int tid = threadIdx.x, lane = tid & 63, wv = tid >> 6;
  int l15 = lane & 15, lq = lane >> 4;
  int wr = wv >> 1, wc = wv & 1;                     // wr 0..3 (64-row slabs), wc 0..1 (64-col)
  f32x4 zero = {0.f,0.f,0.f,0.f};
  f32x4 acc[4][4];
  #pragma unroll
  for (int m=0;m<4;m++)
    #pragma unroll
    for (int n=0;n<4;n++) acc[m][n] = zero;
  const short* srcA[4]; const short* srcB[2];
  #pragma unroll
  for (int i=0;i<4;i++){
    int c = tid + i*512, r = c >> 3, g = (c & 7) ^ (r & 7);
    srcA[i] = A + (size_t)(m0 + r)*Hd + g*8;
  }
  #pragma unroll
  for (int i=0;i<2;i++){
    int c = tid + i*512, r = c >> 3, g = (c & 7) ^ (r & 7);
    srcB[i] = Bt + (size_t)(n0 + r)*Hd + g*8;
  }
  int rsw = l15 & 7;                                 // read-side chunk XOR (row&7 = l15&7)

#define GSTAGE(q_, t_) do { \
    short* bA = (short*)(smem + (q_)*49152); \
    short* bB = bA + 16384; \
    _Pragma("unroll") \
    for (int i=0;i<4;i++) gld16(srcA[i] + (t_)*64, bA + wv*512 + i*4096); \
    _Pragma("unroll") \
    for (int i=0;i<2;i++) gld16(srcB[i] + (t_)*64, bB + wv*512 + i*4096); \
  } while(0)

#define KBODY(q_) do { \
    const short* bA = (const short*)(smem + (q_)*49152); \
    const short* bB = bA + 16384; \
    _Pragma("unroll") \
    for (int kh=0;kh<2;kh++){ \
      s16x8 bf[4]; \
      _Pragma("unroll") \
      for (int n=0;n<4;n++) \
        bf[n] = *(const s16x8*)(bB + (wc*64 + n*16 + l15)*64 + (((kh*4+lq)^rsw)*8)); \
      __builtin_amdgcn_s_setprio(1); \
      _Pragma("unroll") \
      for (int m=0;m<4;m++){ \
        s16x8 af = *(const s16x8*)(bA + (wr*64 + m*16 + l15)*64 + (((kh*4+lq)^rsw)*8)); \
        _Pragma("unroll") \
        for (int n=0;n<4;n++) \
          acc[m][n] = __builtin_amdgcn_mfma_f32_16x16x32_bf16(af, bf[n], acc[m][n], 0, 0, 0); \
      } \
      __builtin_amdgcn_s_setprio(0); \
    } \
  } while(0)

  GSTAGE(0, 0);
  GSTAGE(1, 1);
  int bq = 0;
  for (int t = 0; t < 15; ++t){
    asm volatile("s_waitcnt vmcnt(6)" ::: "memory"); // tile t landed; t+1's 6 stay in flight
    __builtin_amdgcn_s_barrier();                    // cross-wave visibility + buf-reuse safety
    __builtin_amdgcn_sched_barrier(0);
    if (t < 14){
      int bn = bq + 2; if (bn >= 3) bn -= 3;
      GSTAGE(bn, t+2);                               // into buffer consumed at t-1
    }
    KBODY(bq);
    ++bq; if (bq >= 3) bq = 0;
  }
  asm volatile("s_waitcnt vmcnt(0)" ::: "memory");   // peel t=15: full drain
  __builtin_amdgcn_s_barrier();
  __builtin_amdgcn_sched_barrier(0);
  KBODY(bq);
#undef GSTAGE
#undef KBODY
  // ---- epilogue (block-uniform part) ----
  int part = nt >> 3;                                // 0:q 1:k 2:v
  if (part == 2){
    #pragma unroll
    for (int n=0;n<4;n++){
      int c = n0 + wc*64 + n*16 + l15;
      float bv = bias[c];
      int hh = (c >> 6) & 15, d = c & 63;
      #pragma unroll
      for (int m=0;m<4;m++){
        int r0 = m0 + wr*64 + m*16 + lq*4;           // 4 consecutive rows, same b
        int b = r0 >> 11, s0r = r0 & 2047;
        s16x4 o;
        #pragma unroll
        for (int j=0;j<4;j++) o[j] = f2bf(acc[m][n][j] + bv);
        *(s16x4*)(vo + (((size_t)((b*NHd + hh)*Dd + d)) << 11) + s0r) = o;
      }
    }
  } else {
    __syncthreads();                                 // all waves done with ring buffers
    const float* gsp = sp + (size_t)(m0 & 2047)*64;  // block's 256 rows of sin/cos
    #pragma unroll
    for (int u4=0; u4<4; ++u4){
      int u = tid + u4*512;                          // 0..2047
      int sl = u >> 3, dh4 = u & 7;
      f32x4 s4v = *(const f32x4*)(gsp + sl*64 + dh4*4);
      f32x4 c4v = *(const f32x4*)(gsp + sl*64 + 32 + dh4*4);
      float* w8 = sps2 + sl*66 + dh4*8;
      f32x2 p0 = {s4v[0], c4v[0]}, p1 = {s4v[1], c4v[1]};
      f32x2 p2 = {s4v[2], c4v[2]}, p3 = {s4v[3], c4v[3]};
      *(f32x2*)(w8)     = p0; *(f32x2*)(w8 + 2) = p1;
      *(f32x2*)(w8 + 4) = p2; *(f32x2*)(w8 + 6) = p3;
    }
    __syncthreads();
    short* dst = part == 0 ? qo : ko;
    float postscale = part == 0 ? 0.18033688011112042f : 1.0f;  // q: 1/sqrt(64)*log2(e)
    float sgnmul = (l15 & 1) ? 1.0f : -1.0f;         // d parity == l15 parity
    float bvv[4]; int hhv[4], dv[4];
    #pragma unroll
    for (int n=0;n<4;n++){
      int c = n0 + wc*64 + n*16 + l15;
      bvv[n] = bias[c]; hhv[n] = (c >> 6) & 15; dv[n] = c & 63;
    }
    int dh0 = l15 >> 1;                              // d>>1 = n*8 + (l15>>1)
    #pragma unroll
    for (int m=0;m<4;m++){
      #pragma unroll
      for (int j=0;j<4;j++){
        int sl = wr*64 + m*16 + lq*4 + j;            // local row 0..255
        const float* sb = sps2 + sl*66 + dh0*2;
        int r = m0 + sl;
        int b = r >> 11, s = r & 2047;
        #pragma unroll
        for (int n=0;n<4;n++){
          f32x2 sc = *(const f32x2*)(sb + n*16);     // (sin, cos) for d = n*16+l15
          float x = acc[m][n][j] + bvv[n];
          float xp = __shfl_xor(x, 1);               // partner column d^1 (post-bias)
          float y = (x*sc[1] + sgnmul*xp*sc[0]) * postscale;
          dst[(((size_t)((b*NHd + hhv[n])*Sd + s)) << 6) + dv[n]] = f2bf(y);
        }
      }
    }
  }
}

// ---------------- Flash attention: 8 waves x 32 q-rows, KV stage 128 (R15/R16-proven) --
// R17's direct-V read was uncoalesced (4KB lane stride) and regressed 2x -> reverted.
// LDS staging here is the coalescing transform, not just a cache.
__global__ __launch_bounds__(512, 4) void attn_kernel(const short* __restrict__ q,
                                                      const short* __restrict__ k,
                                                      const short* __restrict__ vT,
                                                      float* __restrict__ out){
  __shared__ alignas(16) short kbuf[2][8192];        // [128 kv][64 d], swizzled (32 KB)
  __shared__ alignas(16) short vbuf[2][8192];        // [64 d][128 kv], swizzled (32 KB)
  int bid = blockIdx.x;
  int xcd = bid & 7, w = bid >> 3;                   // same-bh blocks share an XCD's L2
  int bh = xcd*8 + (w >> 3), qb = w & 7;
  int tid = threadIdx.x, lane = tid & 63, wv = tid >> 6;
  int l31 = lane & 31, hi = lane >> 5;
  const short* kp = k  + ((size_t)bh << 17);
  const short* vp = vT + ((size_t)bh << 17);
  int qrow = qb*256 + wv*32 + l31;
  const short* qp = q + ((size_t)bh << 17) + (size_t)qrow*64;
  s16x8 qf[4];                                       // B-frag: col=q(lane&31), k = d = 16*kk+8*hi+i
  #pragma unroll
  for (int kk=0;kk<4;kk++) qf[kk] = *(const s16x8*)(qp + kk*16 + hi*8);
  int kc0 = tid,      kr0 = kc0 >> 3;
  int kc1 = tid+512,  kr1 = kc1 >> 3;
  int koff0 = kr0*64 + ((kc0 ^ kr0) & 7)*8;
  int koff1 = kr1*64 + ((kc1 ^ kr1) & 7)*8;
  int vr0 = tid >> 4,       vcc0 = tid & 15;
  int vr1 = (tid+512) >> 4, vcc1 = (tid+512) & 15;
  int voff0 = vr0*2048 + ((vcc0 & 8) | ((vcc0 ^ vr0) & 7))*8;
  int voff1 = vr1*2048 + ((vcc1 & 8) | ((vcc1 ^ vr1) & 7))*8;

  f32x16 ot0 = z16(), ot1 = z16();                   // O^T: col=q, row = d
  float m = -1e30f, lr = 0.f;                        // lr = own-half partial sum
  int rsw = (l31 & 7);                               // read-side chunk XOR

#define STAGE(nb, t) do { \
    gld16(kp + (size_t)(t)*8192 + koff0, &kbuf[nb][0]    + wv*512); \
    gld16(kp + (size_t)(t)*8192 + koff1, &kbuf[nb][4096] + wv*512); \
    gld16(vp + (size_t)(t)*128  + voff0, &vbuf[nb][0]    + wv*512); \
    gld16(vp + (size_t)(t)*128  + voff1, &vbuf[nb][4096] + wv*512); \
  } while(0)

  STAGE(0, 0);
  __syncthreads();

  for (int t = 0; t < 16; ++t){
    int cur = t & 1;
    if (t < 15) STAGE(cur^1, t+1);                   // drained by barrier at end of t
    #pragma unroll
    for (int h = 0; h < 2; ++h){
      const short* kb = &kbuf[cur][h*4096];
      const short* vb = &vbuf[cur][h*64];
      // ---- S^T = K . Q^T  (two 32x32 kv tiles, contraction d=64) ----
      f32x16 s0 = z16(), s1 = z16();
      __builtin_amdgcn_s_setprio(1);
      #pragma unroll
      for (int kk=0;kk<4;kk++){
        s16x8 kf0 = *(const s16x8*)(kb + l31*64       + (((kk*2 + hi) ^ rsw)*8));
        s0 = __builtin_amdgcn_mfma_f32_32x32x16_bf16(kf0, qf[kk], s0, 0, 0, 0);
        s16x8 kf1 = *(const s16x8*)(kb + (32+l31)*64  + (((kk*2 + hi) ^ rsw)*8));
        s1 = __builtin_amdgcn_mfma_f32_32x32x16_bf16(kf1, qf[kk], s1, 0, 0, 0);
      }
      __builtin_amdgcn_s_setprio(0);
      // ---- online softmax, lane-local per q-row (log2 domain) ----
      float tm[16];
      #pragma unroll
      for (int i=0;i<16;i++) tm[i] = fmaxf(s0[i], s1[i]);
      #pragma unroll
      for (int off=8; off>=1; off>>=1)
        #pragma unroll
        for (int i=0;i<off;i++) tm[i] = fmaxf(tm[i], tm[i+off]);
      float pmax = fmaxf(tm[0], __shfl_xor(tm[0], 32));
      if (!__all(pmax - m <= 8.0f)){                 // defer-max (T13)
        float mn = fmaxf(m, pmax);
        float al = fexp2(m - mn);
        m = mn; lr *= al;
        #pragma unroll
        for (int i=0;i<16;i++){ ot0[i] *= al; ot1[i] *= al; }
      }
      #pragma unroll
      for (int i=0;i<16;i++){ s0[i] = fexp2(s0[i]-m); s1[i] = fexp2(s1[i]-m); }
      float ra[16];
      #pragma unroll
      for (int i=0;i<16;i++) ra[i] = s0[i] + s1[i];
      #pragma unroll
      for (int off=8; off>=1; off>>=1)
        #pragma unroll
        for (int i=0;i<off;i++) ra[i] += ra[i+off];
      lr += ra[0];                                   // own-half partial; combined in epilogue
      // ---- P^T -> bf16 B-frags, O^T += V^T . P^T ----
      #pragma unroll
      for (int s4=0;s4<4;s4++){
        int base = (s4 & 1) * 8;
        int pkA0, pkA1, pkB0, pkB1;
        if (s4 < 2){
          pkA0 = cvtpk(s0[base],   s0[base+1]); pkA1 = cvtpk(s0[base+2], s0[base+3]);
          pkB0 = cvtpk(s0[base+4], s0[base+5]); pkB1 = cvtpk(s0[base+6], s0[base+7]);
        } else {
          pkA0 = cvtpk(s1[base],   s1[base+1]); pkA1 = cvtpk(s1[base+2], s1[base+3]);
          pkB0 = cvtpk(s1[base+4], s1[base+5]); pkB1 = cvtpk(s1[base+6], s1[base+7]);
        }
        int r0 = __shfl_xor(hi ? pkA0 : pkB0, 32);
        int r1 = __shfl_xor(hi ? pkA1 : pkB1, 32);
        union { int wq[4]; s16x8 v8; } u;
        u.wq[0] = hi ? r0   : pkA0;
        u.wq[1] = hi ? r1   : pkA1;
        u.wq[2] = hi ? pkB0 : r0;
        u.wq[3] = hi ? pkB1 : r1;
        __builtin_amdgcn_s_setprio(1);
        s16x8 vf0 = *(const s16x8*)(vb + l31*128      + (((s4*2 + hi) ^ rsw)*8));
        ot0 = __builtin_amdgcn_mfma_f32_32x32x16_bf16(vf0, u.v8, ot0, 0, 0, 0);
        s16x8 vf1 = *(const s16x8*)(vb + (32+l31)*128 + (((s4*2 + hi) ^ rsw)*8));
        ot1 = __builtin_amdgcn_mfma_f32_32x32x16_bf16(vf1, u.v8, ot1, 0, 0, 0);
        __builtin_amdgcn_s_setprio(0);
      }
    }
    __syncthreads();                                 // drains vmcnt (stage) + all waves done with cur
  }
#undef STAGE
  // ---- epilogue: combine halves' lr once; out[b][s=q][h*64 + d] ----
  float lrt = lr + __shfl_xor(lr, 32);
  float inv = 1.0f / lrt;
  int b = bh >> 4, hh = bh & 15;
  float* orow = out + ((size_t)(b*Sd + qrow) << 10) + hh*64;
  #pragma unroll
  for (int g=0; g<4; ++g){
    f32x4 w0, w1;
    #pragma unroll
    for (int j=0;j<4;j++){ w0[j] = ot0[4*g+j]*inv; w1[j] = ot1[4*g+j]*inv; }
    *(f32x4*)(orow + g*8 + 4*hi)      = w0;
    *(f32x4*)(orow + 32 + g*8 + 4*hi) = w1;
  }
}

extern "C" void kernel_launch(void* const* d_in, const int* in_sizes, int n_in,
                              void* d_out, int out_size, void* d_ws, size_t ws_size,
                              hipStream_t stream){
  const float* hs = (const float*)d_in[0];
  const float* sp = (const float*)d_in[1];
  const float* lw = (const float*)d_in[2];
  const float* lb = (const float*)d_in[3];
  const float* wq = (const float*)d_in[4];
  const float* bq = (const float*)d_in[5];
  float* out = (float*)d_out;
  char* ws = (char*)d_ws;
  short* h   = (short*)(ws);
  short* wT  = (short*)(ws + 16777216);
  short* qb_ = (short*)(ws + 23068672);
  short* kb_ = (short*)(ws + 23068672 + 16777216);
  short* vTb = (short*)(ws + 23068672 + 33554432);   // [bh][D][S], written by GEMM epilogue

  hipLaunchKernelGGL(prep_kernel,  dim3(11264),   dim3(256),   0, stream, hs, lw, lb, h, wq, wT);
  hipLaunchKernelGGL(gemm_kernel,  dim3(768),     dim3(512),   0, stream, h, wT, bq, sp, qb_, kb_, vTb);
  hipLaunchKernelGGL(attn_kernel,  dim3(512),     dim3(512),   0, stream, qb_, kb_, vTb, out);
}